// Round 7
// baseline (230.529 us; speedup 1.0000x reference)
//
#include <hip/hip_runtime.h>

typedef unsigned short u16;
typedef unsigned int u32;
typedef __bf16 bf16x8 __attribute__((ext_vector_type(8)));
typedef float f32x4 __attribute__((ext_vector_type(4)));

#define EMB 768
#define NH 12
#define HD 64
#define SEQ 512
#define NB 8
#define NLROWS 4096   // N*L
#define PEROWS 1024   // padded; row 1023 duplicates 1022 (only feeds unused MFMA lanes)

__device__ __forceinline__ float b2f(u16 u) {
    return __uint_as_float(((u32)u) << 16);
}
__device__ __forceinline__ u16 f2b(float f) {
    u32 x = __float_as_uint(f);
    u32 r = x + 0x7fffu + ((x >> 16) & 1u);
    return (u16)(r >> 16);
}
__device__ __forceinline__ u32 pack2(float a, float b) {
    return (u32)f2b(a) | ((u32)f2b(b) << 16);
}
__device__ __forceinline__ bf16x8 ld16(const u16* p) {
    return *(const bf16x8*)p;   // global_load_dwordx4
}
// async global->LDS, 16B per lane; LDS dest = wave-uniform base + lane*16
__device__ __forceinline__ void gl_lds16(const u16* g, u16* l) {
    __builtin_amdgcn_global_load_lds((const __attribute__((address_space(1))) u32*)g,
                                     (__attribute__((address_space(3))) u32*)l, 16, 0, 0);
}

// ---------------------------------------------------------------- prep: transpose5 + pe + cvt3 in one launch
__global__ __launch_bounds__(256) void prep(
        const float* __restrict__ Wq, const float* __restrict__ Wk, const float* __restrict__ Wv,
        const float* __restrict__ Wo, const float* __restrict__ Wpos,
        u16* __restrict__ Wt, u16* __restrict__ pe,
        const float* __restrict__ q, const float* __restrict__ k, const float* __restrict__ v,
        u16* __restrict__ qc, u16* __restrict__ kc, u16* __restrict__ vc) {
    __shared__ u16 tile[32][33];
    int b = blockIdx.x;
    int tid = threadIdx.x;
    if (b < 2880) {
        // transpose+bf16ify the 5 weight matrices
        int m = b / 576, r = b % 576;
        const float* src = (m == 0) ? Wq : (m == 1) ? Wk : (m == 2) ? Wv : (m == 3) ? Wo : Wpos;
        u16* dst = Wt + (size_t)m * EMB * EMB;
        int bx = (r % 24) * 32, by = (r / 24) * 32;
        int tx = tid & 31, ty = tid >> 5;
#pragma unroll
        for (int i = 0; i < 32; i += 8)
            tile[ty + i][tx] = f2b(src[(size_t)(by + ty + i) * EMB + bx + tx]);
        __syncthreads();
#pragma unroll
        for (int i = 0; i < 32; i += 8)
            dst[(size_t)(bx + ty + i) * EMB + by + tx] = tile[tx][ty + i];
    } else if (b < 3904) {
        // sinusoid table rows 0..1023 (1023 dup of 1022)
        int pos = b - 2880;
        int p2 = pos > 1022 ? 1022 : pos;
#pragma unroll
        for (int j = 0; j < 3; j++) {
            int col = tid + j * 256;
            int i = col >> 1;
            float ang = (float)p2 * __expf(-0.023985261384f * (float)i);
            float val = (col & 1) ? __cosf(ang) : __sinf(ang);
            pe[(size_t)pos * EMB + col] = f2b(val);
        }
    } else {
        // fp32 -> bf16 bulk convert q,k,v
        int idx = b - 3904;              // [0, 4608)
        int w = idx / 1536, bx = idx % 1536;
        const float* s = (w == 0) ? q : (w == 1) ? k : v;
        u16* d = (w == 0) ? qc : (w == 1) ? kc : vc;
        size_t i = ((size_t)bx * 256 + tid) * 8;
        float4 f0 = *(const float4*)(s + i);
        float4 f1 = *(const float4*)(s + i + 4);
        uint4 o;
        o.x = pack2(f0.x, f0.y); o.y = pack2(f0.z, f0.w);
        o.z = pack2(f1.x, f1.y); o.w = pack2(f1.z, f1.w);
        *(uint4*)(d + i) = o;
    }
}

// ---------------------------------------------------------------- C[M,768] = A[M,768] @ Bt^T + bias
// BM x BN tile, BK=64, XOR-swizzled unpadded LDS, global_load_lds staging.
// NZ=4: z selects (A,W,bias,C); z==2 writes V^T layout; z==3 is the 1024-row R GEMM.
template <int BM, int BN, int NZ, bool OUTF32>
__global__ __launch_bounds__(256, 4) void gemm_k(
        const u16* A0, const u16* A1, const u16* A2, const u16* A3,
        const u16* W0, const u16* W1, const u16* W2, const u16* W3,
        const float* f0, const float* f1, const float* f2, const float* f3,
        void* C0, void* C1, void* C2, void* C3) {
    constexpr int RT = BM / 32;          // row tiles of 16 per wave
    constexpr int CT = BN / 32;          // col tiles of 16 per wave
    __shared__ __align__(16) u16 As[BM * 64];
    __shared__ __align__(16) u16 Bs[BN * 64];
    int z = (NZ > 1) ? blockIdx.z : 0;
    if (NZ > 1 && z == 3 && blockIdx.x >= PEROWS / BM) return;
    const u16* A = (z == 0) ? A0 : (z == 1) ? A1 : (z == 2) ? A2 : A3;
    const u16* Bt = (z == 0) ? W0 : (z == 1) ? W1 : (z == 2) ? W2 : W3;
    const float* bias = (z == 0) ? f0 : (z == 1) ? f1 : (z == 2) ? f2 : f3;
    void* Cv = (z == 0) ? C0 : (z == 1) ? C1 : (z == 2) ? C2 : C3;
    bool vtout = (NZ > 1) && (z == 2);

    int tid = threadIdx.x;
    int wave = tid >> 6, lane = tid & 63;
    int lrow = lane & 15, lq = lane >> 4;
    int lr8 = lane >> 3, lb = lane & 7;
    int m0 = blockIdx.x * BM, n0 = blockIdx.y * BN;
    int wr = (wave >> 1) * (BM / 2), wc = (wave & 1) * (BN / 2);
    const u16* Abase = A + (size_t)m0 * EMB + (size_t)(lb ^ lr8) * 8;
    const u16* Bbase = Bt + (size_t)n0 * EMB + (size_t)(lb ^ lr8) * 8;
    f32x4 acc[RT][CT] = {};

    for (int k0 = 0; k0 < EMB; k0 += 64) {
        __syncthreads();
#pragma unroll
        for (int j = 0; j < BM / 32; j++) {
            int row = j * 32 + wave * 8 + lr8;
            gl_lds16(Abase + (size_t)row * EMB + k0, &As[(j * 32 + wave * 8) * 64]);
        }
#pragma unroll
        for (int j = 0; j < BN / 32; j++) {
            int row = j * 32 + wave * 8 + lr8;
            gl_lds16(Bbase + (size_t)row * EMB + k0, &Bs[(j * 32 + wave * 8) * 64]);
        }
        __syncthreads();
#pragma unroll
        for (int ks = 0; ks < 2; ks++) {
            int pb = (ks * 4 + lq) ^ (lrow & 7);
            bf16x8 bfr[CT];
#pragma unroll
            for (int ct = 0; ct < CT; ct++)
                bfr[ct] = *(const bf16x8*)&Bs[(wc + ct * 16 + lrow) * 64 + pb * 8];
#pragma unroll
            for (int rt = 0; rt < RT; rt++) {
                bf16x8 afr = *(const bf16x8*)&As[(wr + rt * 16 + lrow) * 64 + pb * 8];
#pragma unroll
                for (int ct = 0; ct < CT; ct++)
                    acc[rt][ct] = __builtin_amdgcn_mfma_f32_16x16x32_bf16(afr, bfr[ct], acc[rt][ct], 0, 0, 0);
            }
        }
    }
#pragma unroll
    for (int rt = 0; rt < RT; rt++) {
#pragma unroll
        for (int ct = 0; ct < CT; ct++) {
            int col = n0 + wc + ct * 16 + lrow;
            float bvv = bias[col];
            int mrow = m0 + wr + rt * 16 + lq * 4;
            if (vtout) {
                // V^T per (n,h): Vtg[((n*12+h)*64 + d)*512 + kv], 4 kv packed
                int nb = mrow >> 9, kvl = mrow & 511;
                int hh = col >> 6, dl = col & 63;
                ushort4 pk;
                pk.x = f2b(acc[rt][ct][0] + bvv);
                pk.y = f2b(acc[rt][ct][1] + bvv);
                pk.z = f2b(acc[rt][ct][2] + bvv);
                pk.w = f2b(acc[rt][ct][3] + bvv);
                *(ushort4*)((u16*)Cv + (((size_t)(nb * NH + hh) * HD + dl) << 9) + kvl) = pk;
            } else if (OUTF32) {
#pragma unroll
                for (int r = 0; r < 4; r++)
                    ((float*)Cv)[(size_t)(mrow + r) * EMB + col] = acc[rt][ct][r] + bvv;
            } else {
#pragma unroll
                for (int r = 0; r < 4; r++)
                    ((u16*)Cv)[(size_t)(mrow + r) * EMB + col] = f2b(acc[rt][ct][r] + bvv);
            }
        }
    }
}

// ---------------------------------------------------------------- fused attention
// block = (q-tile 64, head, batch); wave w owns q rows [w*16, w*16+16).
// ALL K/V/R fragments read directly from global (L2-resident) in MFMA layout:
// no LDS staging, NO per-chunk barriers — waves fully decoupled.
// LDS only: wave-private P round-trip + 256B ls broadcast.
__global__ __launch_bounds__(256, 3) void attn_rpe(
        const u16* __restrict__ Qb, const u16* __restrict__ Kb, const u16* __restrict__ Vtg,
        const u16* __restrict__ Rb, const float* __restrict__ rwb, const float* __restrict__ rrb,
        u16* __restrict__ Ctx) {
    // per-wave region (1664 u16 = 3328 B): Psd[80][20] (1600), later reused as Pb[16][72] (1152)
    __shared__ __align__(16) u16 PsPb[4 * 1664];
    __shared__ float lsb[64];

    int q0 = blockIdx.x * 64;
    int h = blockIdx.y;
    int n = blockIdx.z;
    int tid = threadIdx.x;
    int wave = tid >> 6, lane = tid & 63;
    int lrow = lane & 15, lq = lane >> 4;
    u16* psd = &PsPb[wave * 1664];

    // ---- Q fragments straight from global: aw = Q+rwb, ar = Q+rrb (bf16)
    bf16x8 aw[2], ar[2];
    {
        const u16* qrow = Qb + ((size_t)(n * SEQ + q0 + wave * 16 + lrow)) * EMB + h * HD;
#pragma unroll
        for (int ks = 0; ks < 2; ks++) {
            int c = ks * 32 + lq * 8;
            uint4 qv = *(const uint4*)(qrow + c);
            float4 w0 = *(const float4*)(rwb + h * HD + c);
            float4 w1 = *(const float4*)(rwb + h * HD + c + 4);
            float4 r0 = *(const float4*)(rrb + h * HD + c);
            float4 r1 = *(const float4*)(rrb + h * HD + c + 4);
            union { uint4 u; u16 s[8]; } qu; qu.u = qv;
            union { uint4 u; bf16x8 v; } ww, rr;
            ww.u.x = pack2(b2f(qu.s[0]) + w0.x, b2f(qu.s[1]) + w0.y);
            ww.u.y = pack2(b2f(qu.s[2]) + w0.z, b2f(qu.s[3]) + w0.w);
            ww.u.z = pack2(b2f(qu.s[4]) + w1.x, b2f(qu.s[5]) + w1.y);
            ww.u.w = pack2(b2f(qu.s[6]) + w1.z, b2f(qu.s[7]) + w1.w);
            rr.u.x = pack2(b2f(qu.s[0]) + r0.x, b2f(qu.s[1]) + r0.y);
            rr.u.y = pack2(b2f(qu.s[2]) + r0.z, b2f(qu.s[3]) + r0.w);
            rr.u.z = pack2(b2f(qu.s[4]) + r1.x, b2f(qu.s[5]) + r1.y);
            rr.u.w = pack2(b2f(qu.s[6]) + r1.z, b2f(qu.s[7]) + r1.w);
            aw[ks] = ww.v;
            ar[ks] = rr.v;
        }
    }

    float ls[4] = {0.f, 0.f, 0.f, 0.f};
    f32x4 acco[4] = {};

    for (int c0 = 0; c0 < SEQ; c0 += 64) {
        // direct-global fragment bases for this chunk
        const u16* kbase = Kb + ((size_t)(n * SEQ + c0)) * EMB + h * HD;
        const u16* vbase = Vtg + (((size_t)(n * NH + h) * HD) << 9) + c0;
        const u16* rbase = Rb + (size_t)(q0 - c0 + 448) * EMB + h * HD;  // band rows in [0,1023]

        f32x4 sacc[4] = {};
        f32x4 pacc[5] = {};
        bf16x8 vf[2][4];
#pragma unroll
        for (int ks = 0; ks < 2; ks++) {
            int koff = ks * 32 + lq * 8;
            // K B-frags: B[n=kv][k=d]
            bf16x8 bk[4];
#pragma unroll
            for (int ct = 0; ct < 4; ct++)
                bk[ct] = ld16(kbase + (size_t)(ct * 16 + lrow) * EMB + koff);
            // R B-frags: B[n=t][k=d], banded window per wave
            bf16x8 br[5];
#pragma unroll
            for (int jj = 0; jj < 5; jj++)
                br[jj] = ld16(rbase + (size_t)((wave + jj) * 16 + lrow) * EMB + koff);
            // V A-frags for PV: A[m=d][k=kv] from V^T layout
#pragma unroll
            for (int dt = 0; dt < 4; dt++)
                vf[ks][dt] = ld16(vbase + ((size_t)(dt * 16 + lrow) << 9) + koff);
#pragma unroll
            for (int ct = 0; ct < 4; ct++)
                sacc[ct] = __builtin_amdgcn_mfma_f32_16x16x32_bf16(aw[ks], bk[ct], sacc[ct], 0, 0, 0);
#pragma unroll
            for (int jj = 0; jj < 5; jj++)
                pacc[jj] = __builtin_amdgcn_mfma_f32_16x16x32_bf16(ar[ks], br[jj], pacc[jj], 0, 0, 0);
        }

        // scatter banded P transposed: Psd[jwin][qlocal], one b64 per jj (wave-private region)
#pragma unroll
        for (int jj = 0; jj < 5; jj++) {
            ushort4 pk;
            pk.x = f2b(pacc[jj][0]); pk.y = f2b(pacc[jj][1]);
            pk.z = f2b(pacc[jj][2]); pk.w = f2b(pacc[jj][3]);
            *(ushort4*)&psd[(jj * 16 + lrow) * 20 + lq * 4] = pk;
        }

        // gather bd (all reads complete before Pb overwrites; in-order per-wave DS)
        float bd[4][4];
#pragma unroll
        for (int ct = 0; ct < 4; ct++)
#pragma unroll
            for (int r = 0; r < 4; r++) {
                int jwin = lq * 4 + r - (ct * 16 + lrow) + 63;  // in [0,78]
                bd[ct][r] = b2f(psd[jwin * 20 + lq * 4 + r]);
            }
        // p = 2^((ac+bd)*0.125/ln2) (no max subtraction), row-sum, store Pb[qlocal][k]
#pragma unroll
        for (int ct = 0; ct < 4; ct++)
#pragma unroll
            for (int r = 0; r < 4; r++) {
                float p = exp2f((sacc[ct][r] + bd[ct][r]) * 0.18033688011f);
                ls[r] += p;
                psd[(lq * 4 + r) * 72 + ct * 16 + lrow] = f2b(p);
            }

        // PV operand-swapped: A = V-frag (d rows), B = P-frag (q rows) -> acco[dt] = O[d][q]
#pragma unroll
        for (int ks = 0; ks < 2; ks++) {
            bf16x8 pf = *(const bf16x8*)&psd[lrow * 72 + ks * 32 + lq * 8];
#pragma unroll
            for (int dt = 0; dt < 4; dt++)
                acco[dt] = __builtin_amdgcn_mfma_f32_16x16x32_bf16(vf[ks][dt], pf, acco[dt], 0, 0, 0);
        }
    }

    // epilogue: reduce ls over the 16 k-lanes, broadcast by q (wave-private, in-order DS)
#pragma unroll
    for (int r = 0; r < 4; r++) {
#pragma unroll
        for (int msk = 1; msk < 16; msk <<= 1)
            ls[r] += __shfl_xor(ls[r], msk);
    }
    if (lrow == 0) {
#pragma unroll
        for (int r = 0; r < 4; r++)
            lsb[wave * 16 + lq * 4 + r] = ls[r];
    }
    float inv = 1.0f / lsb[wave * 16 + lrow];
    int q = q0 + wave * 16 + lrow;
#pragma unroll
    for (int dt = 0; dt < 4; dt++) {
        ushort4 pk;
        pk.x = f2b(acco[dt][0] * inv);
        pk.y = f2b(acco[dt][1] * inv);
        pk.z = f2b(acco[dt][2] * inv);
        pk.w = f2b(acco[dt][3] * inv);
        *(ushort4*)&Ctx[((size_t)(n * SEQ + q)) * EMB + h * HD + dt * 16 + lq * 4] = pk;
    }
}

// ----------------------------------------------------------------
extern "C" void kernel_launch(void* const* d_in, const int* in_sizes, int n_in,
                              void* d_out, int out_size, void* d_ws, size_t ws_size,
                              hipStream_t stream) {
    const float* values = (const float*)d_in[0];
    const float* keys   = (const float*)d_in[1];
    const float* query  = (const float*)d_in[2];
    const float* Wq = (const float*)d_in[3];
    const float* bq = (const float*)d_in[4];
    const float* Wk = (const float*)d_in[5];
    const float* bk = (const float*)d_in[6];
    const float* Wv = (const float*)d_in[7];
    const float* bv = (const float*)d_in[8];
    const float* Wo = (const float*)d_in[9];
    const float* bo = (const float*)d_in[10];
    const float* Wpos = (const float*)d_in[11];
    const float* bpos = (const float*)d_in[12];
    const float* rwb = (const float*)d_in[13];
    const float* rrb = (const float*)d_in[14];
    float* out = (float*)d_out;

    u16* ws = (u16*)d_ws;
    size_t off = 0;
    u16* Wt = ws;            off += (size_t)5 * EMB * EMB;   // Wq^T,Wk^T,Wv^T,Wo^T,Wpos^T (bf16)
    u16* pe = ws + off;      off += (size_t)PEROWS * EMB;
    u16* Rb = ws + off;      off += (size_t)PEROWS * EMB;
    u16* qc = ws + off;      off += (size_t)NLROWS * EMB;    // bf16 query
    u16* kc = ws + off;      off += (size_t)NLROWS * EMB;    // bf16 keys
    u16* vc = ws + off;      off += (size_t)NLROWS * EMB;    // bf16 values
    u16* Qp = ws + off;      off += (size_t)NLROWS * EMB;    // Q projection
    u16* Kp = ws + off;      off += (size_t)NLROWS * EMB;    // K projection
    u16* Vtg = ws + off;     off += (size_t)NLROWS * EMB;    // V^T per (n,h): [n][h][d][kv]
    u16* Cx = qc;            // attention output (qc dead after fused GEMM dispatch)

    prep<<<dim3(8512), dim3(256), 0, stream>>>(Wq, Wk, Wv, Wo, Wpos, Wt, pe,
                                               query, keys, values, qc, kc, vc);

    // fused Q/K/V/R projection GEMMs: z = 0:Q 1:K 2:V(->V^T) 3:R(pe@Wpos, 1024 rows)
    gemm_k<128, 96, 4, false><<<dim3(32, 8, 4), dim3(256), 0, stream>>>(
        qc, kc, vc, pe,
        Wt, Wt + (size_t)1 * EMB * EMB, Wt + (size_t)2 * EMB * EMB, Wt + (size_t)4 * EMB * EMB,
        bq, bk, bv, bpos,
        Qp, Kp, Vtg, Rb);

    attn_rpe<<<dim3(8, NH, NB), dim3(256), 0, stream>>>(Qp, Kp, Vtg, Rb, rwb, rrb, Cx);

    gemm_k<64, 96, 1, true><<<dim3(64, 8), dim3(256), 0, stream>>>(
        Cx, Cx, Cx, Cx,
        Wt + (size_t)3 * EMB * EMB, Wt + (size_t)3 * EMB * EMB,
        Wt + (size_t)3 * EMB * EMB, Wt + (size_t)3 * EMB * EMB,
        bo, bo, bo, bo,
        out, out, out, out);
}

// Round 8
// 189.274 us; speedup vs baseline: 1.2180x; 1.2180x over previous
//
#include <hip/hip_runtime.h>

typedef unsigned short u16;
typedef unsigned int u32;
typedef __bf16 bf16x8 __attribute__((ext_vector_type(8)));
typedef float f32x4 __attribute__((ext_vector_type(4)));

#define EMB 768
#define NH 12
#define HD 64
#define SEQ 512
#define NB 8
#define NLROWS 4096   // N*L
#define PEROWS 1024   // padded; row 1023 duplicates 1022 (only feeds unused MFMA lanes)

__device__ __forceinline__ float b2f(u16 u) {
    return __uint_as_float(((u32)u) << 16);
}
__device__ __forceinline__ u16 f2b(float f) {
    u32 x = __float_as_uint(f);
    u32 r = x + 0x7fffu + ((x >> 16) & 1u);
    return (u16)(r >> 16);
}
__device__ __forceinline__ u32 pack2(float a, float b) {
    return (u32)f2b(a) | ((u32)f2b(b) << 16);
}
// async global->LDS, 16B per lane; LDS dest = wave-uniform base + lane*16
__device__ __forceinline__ void gl_lds16(const u16* g, u16* l) {
    __builtin_amdgcn_global_load_lds((const __attribute__((address_space(1))) u32*)g,
                                     (__attribute__((address_space(3))) u32*)l, 16, 0, 0);
}

// ---------------------------------------------------------------- prep: transpose5 + pe + cvt3 in one launch
__global__ __launch_bounds__(256) void prep(
        const float* __restrict__ Wq, const float* __restrict__ Wk, const float* __restrict__ Wv,
        const float* __restrict__ Wo, const float* __restrict__ Wpos,
        u16* __restrict__ Wt, u16* __restrict__ pe,
        const float* __restrict__ q, const float* __restrict__ k, const float* __restrict__ v,
        u16* __restrict__ qc, u16* __restrict__ kc, u16* __restrict__ vc) {
    __shared__ u16 tile[32][33];
    int b = blockIdx.x;
    int tid = threadIdx.x;
    if (b < 2880) {
        // transpose+bf16ify the 5 weight matrices
        int m = b / 576, r = b % 576;
        const float* src = (m == 0) ? Wq : (m == 1) ? Wk : (m == 2) ? Wv : (m == 3) ? Wo : Wpos;
        u16* dst = Wt + (size_t)m * EMB * EMB;
        int bx = (r % 24) * 32, by = (r / 24) * 32;
        int tx = tid & 31, ty = tid >> 5;
#pragma unroll
        for (int i = 0; i < 32; i += 8)
            tile[ty + i][tx] = f2b(src[(size_t)(by + ty + i) * EMB + bx + tx]);
        __syncthreads();
#pragma unroll
        for (int i = 0; i < 32; i += 8)
            dst[(size_t)(bx + ty + i) * EMB + by + tx] = tile[tx][ty + i];
    } else if (b < 3904) {
        // sinusoid table rows 0..1023 (1023 dup of 1022)
        int pos = b - 2880;
        int p2 = pos > 1022 ? 1022 : pos;
#pragma unroll
        for (int j = 0; j < 3; j++) {
            int col = tid + j * 256;
            int i = col >> 1;
            float ang = (float)p2 * __expf(-0.023985261384f * (float)i);
            float val = (col & 1) ? __cosf(ang) : __sinf(ang);
            pe[(size_t)pos * EMB + col] = f2b(val);
        }
    } else {
        // fp32 -> bf16 bulk convert q,k,v
        int idx = b - 3904;              // [0, 4608)
        int w = idx / 1536, bx = idx % 1536;
        const float* s = (w == 0) ? q : (w == 1) ? k : v;
        u16* d = (w == 0) ? qc : (w == 1) ? kc : vc;
        size_t i = ((size_t)bx * 256 + tid) * 8;
        float4 f0 = *(const float4*)(s + i);
        float4 f1 = *(const float4*)(s + i + 4);
        uint4 o;
        o.x = pack2(f0.x, f0.y); o.y = pack2(f0.z, f0.w);
        o.z = pack2(f1.x, f1.y); o.w = pack2(f1.z, f1.w);
        *(uint4*)(d + i) = o;
    }
}

// ---------------------------------------------------------------- C[M,768] = A[M,768] @ Bt^T + bias
// BM x BN tile, BK=64, XOR-swizzled unpadded LDS, global_load_lds staging.
// 1D XCD-swizzled virtual grid:
//  MODE 0 (QKVR, 832 blocks): t<768 -> QKV: r=t&7, u=t>>3, x=u&31, p=(u>>5)*8+r, y=p/3, z=p%3
//                              (all 32 x-blocks of one (y,z) B-panel share t%8 -> same XCD)
//                              t>=768 -> R GEMM (z=3): x=(t-768)&7, y=(t-768)>>3
//  MODE 1 (single, 512 blocks): y=t&7, x=t>>3 (64 x-sharers of a B-panel on one XCD)
template <int BM, int BN, int MODE, bool OUTF32>
__global__ __launch_bounds__(256, 4) void gemm_k(
        const u16* A0, const u16* A1, const u16* A2, const u16* A3,
        const u16* W0, const u16* W1, const u16* W2, const u16* W3,
        const float* f0, const float* f1, const float* f2, const float* f3,
        void* C0, void* C1, void* C2, void* C3) {
    constexpr int RT = BM / 32;          // row tiles of 16 per wave
    constexpr int CT = BN / 32;          // col tiles of 16 per wave
    __shared__ __align__(16) u16 As[BM * 64];
    __shared__ __align__(16) u16 Bs[BN * 64];
    int t = blockIdx.x;
    int x, y, z;
    if (MODE == 0) {
        if (t < 768) {
            int r = t & 7, u = t >> 3;
            x = u & 31;
            int p = (u >> 5) * 8 + r;
            y = p / 3; z = p % 3;
        } else {
            int u = t - 768;
            x = u & 7; y = u >> 3; z = 3;
        }
    } else {
        y = t & 7; x = t >> 3; z = 0;
    }
    const u16* A = (z == 0) ? A0 : (z == 1) ? A1 : (z == 2) ? A2 : A3;
    const u16* Bt = (z == 0) ? W0 : (z == 1) ? W1 : (z == 2) ? W2 : W3;
    const float* bias = (z == 0) ? f0 : (z == 1) ? f1 : (z == 2) ? f2 : f3;
    void* Cv = (z == 0) ? C0 : (z == 1) ? C1 : (z == 2) ? C2 : C3;
    bool vtout = (MODE == 0) && (z == 2);

    int tid = threadIdx.x;
    int wave = tid >> 6, lane = tid & 63;
    int lrow = lane & 15, lq = lane >> 4;
    int lr8 = lane >> 3, lb = lane & 7;
    int m0 = x * BM, n0 = y * BN;
    int wr = (wave >> 1) * (BM / 2), wc = (wave & 1) * (BN / 2);
    const u16* Abase = A + (size_t)m0 * EMB + (size_t)(lb ^ lr8) * 8;
    const u16* Bbase = Bt + (size_t)n0 * EMB + (size_t)(lb ^ lr8) * 8;
    f32x4 acc[RT][CT] = {};

    for (int k0 = 0; k0 < EMB; k0 += 64) {
        __syncthreads();
#pragma unroll
        for (int j = 0; j < BM / 32; j++) {
            int row = j * 32 + wave * 8 + lr8;
            gl_lds16(Abase + (size_t)row * EMB + k0, &As[(j * 32 + wave * 8) * 64]);
        }
#pragma unroll
        for (int j = 0; j < BN / 32; j++) {
            int row = j * 32 + wave * 8 + lr8;
            gl_lds16(Bbase + (size_t)row * EMB + k0, &Bs[(j * 32 + wave * 8) * 64]);
        }
        __syncthreads();
#pragma unroll
        for (int ks = 0; ks < 2; ks++) {
            int pb = (ks * 4 + lq) ^ (lrow & 7);
            bf16x8 bfr[CT];
#pragma unroll
            for (int ct = 0; ct < CT; ct++)
                bfr[ct] = *(const bf16x8*)&Bs[(wc + ct * 16 + lrow) * 64 + pb * 8];
#pragma unroll
            for (int rt = 0; rt < RT; rt++) {
                bf16x8 afr = *(const bf16x8*)&As[(wr + rt * 16 + lrow) * 64 + pb * 8];
#pragma unroll
                for (int ct = 0; ct < CT; ct++)
                    acc[rt][ct] = __builtin_amdgcn_mfma_f32_16x16x32_bf16(afr, bfr[ct], acc[rt][ct], 0, 0, 0);
            }
        }
    }
#pragma unroll
    for (int rt = 0; rt < RT; rt++) {
#pragma unroll
        for (int ct = 0; ct < CT; ct++) {
            int col = n0 + wc + ct * 16 + lrow;
            float bvv = bias[col];
            int mrow = m0 + wr + rt * 16 + lq * 4;
            if (vtout) {
                // V^T per (n,h): Vtg[((n*12+h)*64 + d)*512 + kv], 4 kv packed
                int nb = mrow >> 9, kvl = mrow & 511;
                int hh = col >> 6, dl = col & 63;
                ushort4 pk;
                pk.x = f2b(acc[rt][ct][0] + bvv);
                pk.y = f2b(acc[rt][ct][1] + bvv);
                pk.z = f2b(acc[rt][ct][2] + bvv);
                pk.w = f2b(acc[rt][ct][3] + bvv);
                *(ushort4*)((u16*)Cv + (((size_t)(nb * NH + hh) * HD + dl) << 9) + kvl) = pk;
            } else if (OUTF32) {
#pragma unroll
                for (int r = 0; r < 4; r++)
                    ((float*)Cv)[(size_t)(mrow + r) * EMB + col] = acc[rt][ct][r] + bvv;
            } else {
#pragma unroll
                for (int r = 0; r < 4; r++)
                    ((u16*)Cv)[(size_t)(mrow + r) * EMB + col] = f2b(acc[rt][ct][r] + bvv);
            }
        }
    }
}

// ---------------------------------------------------------------- fused attention (R6 version, reverted from R7)
// block = (q-tile 64, head, batch); wave w owns q rows [w*16, w*16+16).
// No-max softmax; producer-overlap staging; per-wave transposed P-band (vector scatter);
// PV operand-swapped (acc holds d-consecutive) -> ushort4 epilogue.
__global__ __launch_bounds__(256, 3) void attn_rpe(
        const u16* __restrict__ Qb, const u16* __restrict__ Kb, const u16* __restrict__ Vtg,
        const u16* __restrict__ Rb, const float* __restrict__ rwb, const float* __restrict__ rrb,
        u16* __restrict__ Ctx) {
    __shared__ __align__(16) u16 Ks[64 * 64];
    __shared__ __align__(16) u16 Vt[64 * 64];
    __shared__ __align__(16) u16 Rs[128 * 64];
    // per-wave region (1664 u16 = 3328 B): Psd[80][20] (1600), later reused as Pb[16][72] (1152)
    __shared__ __align__(16) u16 PsPb[4 * 1664];

    int q0 = blockIdx.x * 64;
    int h = blockIdx.y;
    int n = blockIdx.z;
    int tid = threadIdx.x;
    int wave = tid >> 6, lane = tid & 63;
    int lrow = lane & 15, lq = lane >> 4;
    int lr8 = lane >> 3, lb = lane & 7;
    int swz = (lb ^ lr8) * 8;
    u16* psd = &PsPb[wave * 1664];

    // ---- Q fragments straight from global: aw = Q+rwb, ar = Q+rrb (bf16)
    bf16x8 aw[2], ar[2];
    {
        const u16* qrow = Qb + ((size_t)(n * SEQ + q0 + wave * 16 + lrow)) * EMB + h * HD;
#pragma unroll
        for (int ks = 0; ks < 2; ks++) {
            int c = ks * 32 + lq * 8;
            uint4 qv = *(const uint4*)(qrow + c);
            float4 w0 = *(const float4*)(rwb + h * HD + c);
            float4 w1 = *(const float4*)(rwb + h * HD + c + 4);
            float4 r0 = *(const float4*)(rrb + h * HD + c);
            float4 r1 = *(const float4*)(rrb + h * HD + c + 4);
            union { uint4 u; u16 s[8]; } qu; qu.u = qv;
            union { uint4 u; bf16x8 v; } ww, rr;
            ww.u.x = pack2(b2f(qu.s[0]) + w0.x, b2f(qu.s[1]) + w0.y);
            ww.u.y = pack2(b2f(qu.s[2]) + w0.z, b2f(qu.s[3]) + w0.w);
            ww.u.z = pack2(b2f(qu.s[4]) + w1.x, b2f(qu.s[5]) + w1.y);
            ww.u.w = pack2(b2f(qu.s[6]) + w1.z, b2f(qu.s[7]) + w1.w);
            rr.u.x = pack2(b2f(qu.s[0]) + r0.x, b2f(qu.s[1]) + r0.y);
            rr.u.y = pack2(b2f(qu.s[2]) + r0.z, b2f(qu.s[3]) + r0.w);
            rr.u.z = pack2(b2f(qu.s[4]) + r1.x, b2f(qu.s[5]) + r1.y);
            rr.u.w = pack2(b2f(qu.s[6]) + r1.z, b2f(qu.s[7]) + r1.w);
            aw[ks] = ww.v;
            ar[ks] = rr.v;
        }
    }

    auto stage_chunk = [&](int cc) {
#pragma unroll
        for (int j = 0; j < 2; j++) {      // K tile [kv][d]
            int row = j * 32 + wave * 8 + lr8;
            gl_lds16(Kb + ((size_t)(n * SEQ + cc + row)) * EMB + h * HD + swz,
                     &Ks[(j * 32 + wave * 8) * 64]);
        }
#pragma unroll
        for (int j = 0; j < 2; j++) {      // V^T tile [d][kv]
            int row = j * 32 + wave * 8 + lr8;
            gl_lds16(Vtg + (((size_t)(n * NH + h) * HD + row) << 9) + cc + swz,
                     &Vt[(j * 32 + wave * 8) * 64]);
        }
#pragma unroll
        for (int j = 0; j < 4; j++) {      // R band rows t0..t0+127, t0 = q0-cc+448 in [0,1023]
            int row = j * 32 + wave * 8 + lr8;
            gl_lds16(Rb + (size_t)(q0 - cc + 448 + row) * EMB + h * HD + swz,
                     &Rs[(j * 32 + wave * 8) * 64]);
        }
    };

    float ls[4] = {0.f, 0.f, 0.f, 0.f};
    f32x4 acco[4] = {};

    stage_chunk(0);
    for (int c0 = 0; c0 < SEQ; c0 += 64) {
        __syncthreads();  // staging complete (vmcnt drained at barrier); prior LDS reads done

        f32x4 sacc[4] = {};
        f32x4 pacc[5] = {};
        bf16x8 vf[2][4];
#pragma unroll
        for (int ks = 0; ks < 2; ks++) {
            int pb = (ks * 4 + lq) ^ (lrow & 7);
#pragma unroll
            for (int ct = 0; ct < 4; ct++) {
                bf16x8 bk = *(const bf16x8*)&Ks[(ct * 16 + lrow) * 64 + pb * 8];
                sacc[ct] = __builtin_amdgcn_mfma_f32_16x16x32_bf16(aw[ks], bk, sacc[ct], 0, 0, 0);
            }
#pragma unroll
            for (int jj = 0; jj < 5; jj++) {
                bf16x8 br = *(const bf16x8*)&Rs[((wave + jj) * 16 + lrow) * 64 + pb * 8];
                pacc[jj] = __builtin_amdgcn_mfma_f32_16x16x32_bf16(ar[ks], br, pacc[jj], 0, 0, 0);
            }
#pragma unroll
            for (int dt = 0; dt < 4; dt++)
                vf[ks][dt] = *(const bf16x8*)&Vt[(dt * 16 + lrow) * 64 + pb * 8];
        }
        __syncthreads();  // all waves done reading Ks/Vt/Rs
        if (c0 + 64 < SEQ) stage_chunk(c0 + 64);  // overlaps the softmax/PV phase below

        // scatter banded P transposed: Psd[jwin][qlocal], one b64 per jj (wave-private region)
#pragma unroll
        for (int jj = 0; jj < 5; jj++) {
            ushort4 pk;
            pk.x = f2b(pacc[jj][0]); pk.y = f2b(pacc[jj][1]);
            pk.z = f2b(pacc[jj][2]); pk.w = f2b(pacc[jj][3]);
            *(ushort4*)&psd[(jj * 16 + lrow) * 20 + lq * 4] = pk;
        }

        // gather bd (all reads before Pb overwrites the region; in-order per-wave DS)
        float bd[4][4];
#pragma unroll
        for (int ct = 0; ct < 4; ct++)
#pragma unroll
            for (int r = 0; r < 4; r++) {
                int jwin = lq * 4 + r - (ct * 16 + lrow) + 63;  // in [0,78]
                bd[ct][r] = b2f(psd[jwin * 20 + lq * 4 + r]);
            }
        // p = 2^((ac+bd)*0.125/ln2) (no max subtraction), row-sum, store Pb[qlocal][k]
#pragma unroll
        for (int ct = 0; ct < 4; ct++)
#pragma unroll
            for (int r = 0; r < 4; r++) {
                float p = exp2f((sacc[ct][r] + bd[ct][r]) * 0.18033688011f);
                ls[r] += p;
                psd[(lq * 4 + r) * 72 + ct * 16 + lrow] = f2b(p);
            }

        // PV operand-swapped: A = V-frag (d rows), B = P-frag (q rows) -> acco[dt] = O[d][q]
#pragma unroll
        for (int ks = 0; ks < 2; ks++) {
            bf16x8 pf = *(const bf16x8*)&psd[lrow * 72 + ks * 32 + lq * 8];
#pragma unroll
            for (int dt = 0; dt < 4; dt++)
                acco[dt] = __builtin_amdgcn_mfma_f32_16x16x32_bf16(vf[ks][dt], pf, acco[dt], 0, 0, 0);
        }
    }

    // epilogue: reduce ls over the 16 k-lanes, broadcast by q via dead Rs, ushort4 stores
#pragma unroll
    for (int r = 0; r < 4; r++) {
#pragma unroll
        for (int msk = 1; msk < 16; msk <<= 1)
            ls[r] += __shfl_xor(ls[r], msk);
    }
    float* lsb = (float*)Rs;
    if (lrow == 0) {
#pragma unroll
        for (int r = 0; r < 4; r++)
            lsb[wave * 16 + lq * 4 + r] = ls[r];
    }
    float inv = 1.0f / lsb[wave * 16 + lrow];  // wave-private write->read, in-order DS
    int q = q0 + wave * 16 + lrow;
#pragma unroll
    for (int dt = 0; dt < 4; dt++) {
        ushort4 pk;
        pk.x = f2b(acco[dt][0] * inv);
        pk.y = f2b(acco[dt][1] * inv);
        pk.z = f2b(acco[dt][2] * inv);
        pk.w = f2b(acco[dt][3] * inv);
        *(ushort4*)&Ctx[((size_t)(n * SEQ + q)) * EMB + h * HD + dt * 16 + lq * 4] = pk;
    }
}

// ----------------------------------------------------------------
extern "C" void kernel_launch(void* const* d_in, const int* in_sizes, int n_in,
                              void* d_out, int out_size, void* d_ws, size_t ws_size,
                              hipStream_t stream) {
    const float* values = (const float*)d_in[0];
    const float* keys   = (const float*)d_in[1];
    const float* query  = (const float*)d_in[2];
    const float* Wq = (const float*)d_in[3];
    const float* bq = (const float*)d_in[4];
    const float* Wk = (const float*)d_in[5];
    const float* bk = (const float*)d_in[6];
    const float* Wv = (const float*)d_in[7];
    const float* bv = (const float*)d_in[8];
    const float* Wo = (const float*)d_in[9];
    const float* bo = (const float*)d_in[10];
    const float* Wpos = (const float*)d_in[11];
    const float* bpos = (const float*)d_in[12];
    const float* rwb = (const float*)d_in[13];
    const float* rrb = (const float*)d_in[14];
    float* out = (float*)d_out;

    u16* ws = (u16*)d_ws;
    size_t off = 0;
    u16* Wt = ws;            off += (size_t)5 * EMB * EMB;   // Wq^T,Wk^T,Wv^T,Wo^T,Wpos^T (bf16)
    u16* pe = ws + off;      off += (size_t)PEROWS * EMB;
    u16* Rb = ws + off;      off += (size_t)PEROWS * EMB;
    u16* qc = ws + off;      off += (size_t)NLROWS * EMB;    // bf16 query
    u16* kc = ws + off;      off += (size_t)NLROWS * EMB;    // bf16 keys
    u16* vc = ws + off;      off += (size_t)NLROWS * EMB;    // bf16 values
    u16* Qp = ws + off;      off += (size_t)NLROWS * EMB;    // Q projection
    u16* Kp = ws + off;      off += (size_t)NLROWS * EMB;    // K projection
    u16* Vtg = ws + off;     off += (size_t)NLROWS * EMB;    // V^T per (n,h): [n][h][d][kv]
    u16* Cx = qc;            // attention output (qc dead after fused GEMM dispatch)

    prep<<<dim3(8512), dim3(256), 0, stream>>>(Wq, Wk, Wv, Wo, Wpos, Wt, pe,
                                               query, keys, values, qc, kc, vc);

    // fused Q/K/V/R projection GEMMs, 1D XCD-swizzled grid (832 working blocks, no early-exit waste)
    gemm_k<128, 96, 0, false><<<dim3(832), dim3(256), 0, stream>>>(
        qc, kc, vc, pe,
        Wt, Wt + (size_t)1 * EMB * EMB, Wt + (size_t)2 * EMB * EMB, Wt + (size_t)4 * EMB * EMB,
        bq, bk, bv, bpos,
        Qp, Kp, Vtg, Rb);

    attn_rpe<<<dim3(8, NH, NB), dim3(256), 0, stream>>>(Qp, Kp, Vtg, Rb, rwb, rrb, Cx);

    gemm_k<64, 96, 1, true><<<dim3(512), dim3(256), 0, stream>>>(
        Cx, Cx, Cx, Cx,
        Wt + (size_t)3 * EMB * EMB, Wt + (size_t)3 * EMB * EMB,
        Wt + (size_t)3 * EMB * EMB, Wt + (size_t)3 * EMB * EMB,
        bo, bo, bo, bo,
        out, out, out, out);
}

// Round 9
// 178.983 us; speedup vs baseline: 1.2880x; 1.0575x over previous
//
#include <hip/hip_runtime.h>

typedef unsigned short u16;
typedef unsigned int u32;
typedef __bf16 bf16x8 __attribute__((ext_vector_type(8)));
typedef float f32x4 __attribute__((ext_vector_type(4)));

#define EMB 768
#define NH 12
#define HD 64
#define SEQ 512
#define NB 8
#define NLROWS 4096   // N*L
#define PEROWS 1024   // padded; row 1023 duplicates 1022 (only feeds unused MFMA lanes)

__device__ __forceinline__ float b2f(u16 u) {
    return __uint_as_float(((u32)u) << 16);
}
__device__ __forceinline__ u16 f2b(float f) {
    u32 x = __float_as_uint(f);
    u32 r = x + 0x7fffu + ((x >> 16) & 1u);
    return (u16)(r >> 16);
}
__device__ __forceinline__ u32 pack2(float a, float b) {
    return (u32)f2b(a) | ((u32)f2b(b) << 16);
}
// async global->LDS, 16B per lane; LDS dest = wave-uniform base + lane*16
__device__ __forceinline__ void gl_lds16(const u16* g, u16* l) {
    __builtin_amdgcn_global_load_lds((const __attribute__((address_space(1))) u32*)g,
                                     (__attribute__((address_space(3))) u32*)l, 16, 0, 0);
}

// ---------------------------------------------------------------- prep: transpose5 + pe + cvt3 in one launch
__global__ __launch_bounds__(256) void prep(
        const float* __restrict__ Wq, const float* __restrict__ Wk, const float* __restrict__ Wv,
        const float* __restrict__ Wo, const float* __restrict__ Wpos,
        u16* __restrict__ Wt, u16* __restrict__ pe,
        const float* __restrict__ q, const float* __restrict__ k, const float* __restrict__ v,
        u16* __restrict__ qc, u16* __restrict__ kc, u16* __restrict__ vc) {
    __shared__ u16 tile[32][33];
    int b = blockIdx.x;
    int tid = threadIdx.x;
    if (b < 2880) {
        // transpose+bf16ify the 5 weight matrices
        int m = b / 576, r = b % 576;
        const float* src = (m == 0) ? Wq : (m == 1) ? Wk : (m == 2) ? Wv : (m == 3) ? Wo : Wpos;
        u16* dst = Wt + (size_t)m * EMB * EMB;
        int bx = (r % 24) * 32, by = (r / 24) * 32;
        int tx = tid & 31, ty = tid >> 5;
#pragma unroll
        for (int i = 0; i < 32; i += 8)
            tile[ty + i][tx] = f2b(src[(size_t)(by + ty + i) * EMB + bx + tx]);
        __syncthreads();
        // write side: 2 consecutive out-cols per lane -> u32 stores (2x wider than scalar u16)
        int c2 = (tid & 15) * 2, rw = tid >> 4;
#pragma unroll
        for (int i = 0; i < 32; i += 16) {
            int row = rw + i;
            u32 val = (u32)tile[c2][row] | ((u32)tile[c2 + 1][row] << 16);
            *(u32*)&dst[(size_t)(bx + row) * EMB + by + c2] = val;
        }
    } else if (b < 3904) {
        // sinusoid table rows 0..1023 (1023 dup of 1022)
        int pos = b - 2880;
        int p2 = pos > 1022 ? 1022 : pos;
#pragma unroll
        for (int j = 0; j < 3; j++) {
            int col = tid + j * 256;
            int i = col >> 1;
            float ang = (float)p2 * __expf(-0.023985261384f * (float)i);
            float val = (col & 1) ? __cosf(ang) : __sinf(ang);
            pe[(size_t)pos * EMB + col] = f2b(val);
        }
    } else {
        // fp32 -> bf16 bulk convert q,k,v
        int idx = b - 3904;              // [0, 4608)
        int w = idx / 1536, bx = idx % 1536;
        const float* s = (w == 0) ? q : (w == 1) ? k : v;
        u16* d = (w == 0) ? qc : (w == 1) ? kc : vc;
        size_t i = ((size_t)bx * 256 + tid) * 8;
        float4 f0 = *(const float4*)(s + i);
        float4 f1 = *(const float4*)(s + i + 4);
        uint4 o;
        o.x = pack2(f0.x, f0.y); o.y = pack2(f0.z, f0.w);
        o.z = pack2(f1.x, f1.y); o.w = pack2(f1.z, f1.w);
        *(uint4*)(d + i) = o;
    }
}

// ---------------------------------------------------------------- C[M,768] = A[M,768] @ Bt^T + bias
// BM x BN tile, BK=64, XOR-swizzled unpadded LDS, global_load_lds staging.
// NZ=4: z selects (A,W,bias,C); z==2 writes V^T layout; z==3 is the 1024-row R GEMM.
template <int BM, int BN, int NZ, bool OUTF32>
__global__ __launch_bounds__(256, 4) void gemm_k(
        const u16* A0, const u16* A1, const u16* A2, const u16* A3,
        const u16* W0, const u16* W1, const u16* W2, const u16* W3,
        const float* f0, const float* f1, const float* f2, const float* f3,
        void* C0, void* C1, void* C2, void* C3) {
    constexpr int RT = BM / 32;          // row tiles of 16 per wave
    constexpr int CT = BN / 32;          // col tiles of 16 per wave
    __shared__ __align__(16) u16 As[BM * 64];
    __shared__ __align__(16) u16 Bs[BN * 64];
    int z = (NZ > 1) ? blockIdx.z : 0;
    if (NZ > 1 && z == 3 && blockIdx.x >= PEROWS / BM) return;
    const u16* A = (z == 0) ? A0 : (z == 1) ? A1 : (z == 2) ? A2 : A3;
    const u16* Bt = (z == 0) ? W0 : (z == 1) ? W1 : (z == 2) ? W2 : W3;
    const float* bias = (z == 0) ? f0 : (z == 1) ? f1 : (z == 2) ? f2 : f3;
    void* Cv = (z == 0) ? C0 : (z == 1) ? C1 : (z == 2) ? C2 : C3;
    bool vtout = (NZ > 1) && (z == 2);

    int tid = threadIdx.x;
    int wave = tid >> 6, lane = tid & 63;
    int lrow = lane & 15, lq = lane >> 4;
    int lr8 = lane >> 3, lb = lane & 7;
    int m0 = blockIdx.x * BM, n0 = blockIdx.y * BN;
    int wr = (wave >> 1) * (BM / 2), wc = (wave & 1) * (BN / 2);
    const u16* Abase = A + (size_t)m0 * EMB + (size_t)(lb ^ lr8) * 8;
    const u16* Bbase = Bt + (size_t)n0 * EMB + (size_t)(lb ^ lr8) * 8;
    f32x4 acc[RT][CT] = {};

    for (int k0 = 0; k0 < EMB; k0 += 64) {
        __syncthreads();
#pragma unroll
        for (int j = 0; j < BM / 32; j++) {
            int row = j * 32 + wave * 8 + lr8;
            gl_lds16(Abase + (size_t)row * EMB + k0, &As[(j * 32 + wave * 8) * 64]);
        }
#pragma unroll
        for (int j = 0; j < BN / 32; j++) {
            int row = j * 32 + wave * 8 + lr8;
            gl_lds16(Bbase + (size_t)row * EMB + k0, &Bs[(j * 32 + wave * 8) * 64]);
        }
        __syncthreads();
#pragma unroll
        for (int ks = 0; ks < 2; ks++) {
            int pb = (ks * 4 + lq) ^ (lrow & 7);
            bf16x8 bfr[CT];
#pragma unroll
            for (int ct = 0; ct < CT; ct++)
                bfr[ct] = *(const bf16x8*)&Bs[(wc + ct * 16 + lrow) * 64 + pb * 8];
#pragma unroll
            for (int rt = 0; rt < RT; rt++) {
                bf16x8 afr = *(const bf16x8*)&As[(wr + rt * 16 + lrow) * 64 + pb * 8];
#pragma unroll
                for (int ct = 0; ct < CT; ct++)
                    acc[rt][ct] = __builtin_amdgcn_mfma_f32_16x16x32_bf16(afr, bfr[ct], acc[rt][ct], 0, 0, 0);
            }
        }
    }
#pragma unroll
    for (int rt = 0; rt < RT; rt++) {
#pragma unroll
        for (int ct = 0; ct < CT; ct++) {
            int col = n0 + wc + ct * 16 + lrow;
            float bvv = bias[col];
            int mrow = m0 + wr + rt * 16 + lq * 4;
            if (vtout) {
                // V^T per (n,h): Vtg[((n*12+h)*64 + d)*512 + kv], 4 kv packed
                int nb = mrow >> 9, kvl = mrow & 511;
                int hh = col >> 6, dl = col & 63;
                ushort4 pk;
                pk.x = f2b(acc[rt][ct][0] + bvv);
                pk.y = f2b(acc[rt][ct][1] + bvv);
                pk.z = f2b(acc[rt][ct][2] + bvv);
                pk.w = f2b(acc[rt][ct][3] + bvv);
                *(ushort4*)((u16*)Cv + (((size_t)(nb * NH + hh) * HD + dl) << 9) + kvl) = pk;
            } else if (OUTF32) {
#pragma unroll
                for (int r = 0; r < 4; r++)
                    ((float*)Cv)[(size_t)(mrow + r) * EMB + col] = acc[rt][ct][r] + bvv;
            } else {
#pragma unroll
                for (int r = 0; r < 4; r++)
                    ((u16*)Cv)[(size_t)(mrow + r) * EMB + col] = f2b(acc[rt][ct][r] + bvv);
            }
        }
    }
}

// ---------------------------------------------------------------- fused attention (R6 version)
// block = (q-tile 64, head, batch); wave w owns q rows [w*16, w*16+16).
// No-max softmax; producer-overlap staging; per-wave transposed P-band (vector scatter);
// PV operand-swapped (acc holds d-consecutive) -> ushort4 epilogue.
__global__ __launch_bounds__(256, 3) void attn_rpe(
        const u16* __restrict__ Qb, const u16* __restrict__ Kb, const u16* __restrict__ Vtg,
        const u16* __restrict__ Rb, const float* __restrict__ rwb, const float* __restrict__ rrb,
        u16* __restrict__ Ctx) {
    __shared__ __align__(16) u16 Ks[64 * 64];
    __shared__ __align__(16) u16 Vt[64 * 64];
    __shared__ __align__(16) u16 Rs[128 * 64];
    // per-wave region (1664 u16 = 3328 B): Psd[80][20] (1600), later reused as Pb[16][72] (1152)
    __shared__ __align__(16) u16 PsPb[4 * 1664];

    int q0 = blockIdx.x * 64;
    int h = blockIdx.y;
    int n = blockIdx.z;
    int tid = threadIdx.x;
    int wave = tid >> 6, lane = tid & 63;
    int lrow = lane & 15, lq = lane >> 4;
    int lr8 = lane >> 3, lb = lane & 7;
    int swz = (lb ^ lr8) * 8;
    u16* psd = &PsPb[wave * 1664];

    // ---- Q fragments straight from global: aw = Q+rwb, ar = Q+rrb (bf16)
    bf16x8 aw[2], ar[2];
    {
        const u16* qrow = Qb + ((size_t)(n * SEQ + q0 + wave * 16 + lrow)) * EMB + h * HD;
#pragma unroll
        for (int ks = 0; ks < 2; ks++) {
            int c = ks * 32 + lq * 8;
            uint4 qv = *(const uint4*)(qrow + c);
            float4 w0 = *(const float4*)(rwb + h * HD + c);
            float4 w1 = *(const float4*)(rwb + h * HD + c + 4);
            float4 r0 = *(const float4*)(rrb + h * HD + c);
            float4 r1 = *(const float4*)(rrb + h * HD + c + 4);
            union { uint4 u; u16 s[8]; } qu; qu.u = qv;
            union { uint4 u; bf16x8 v; } ww, rr;
            ww.u.x = pack2(b2f(qu.s[0]) + w0.x, b2f(qu.s[1]) + w0.y);
            ww.u.y = pack2(b2f(qu.s[2]) + w0.z, b2f(qu.s[3]) + w0.w);
            ww.u.z = pack2(b2f(qu.s[4]) + w1.x, b2f(qu.s[5]) + w1.y);
            ww.u.w = pack2(b2f(qu.s[6]) + w1.z, b2f(qu.s[7]) + w1.w);
            rr.u.x = pack2(b2f(qu.s[0]) + r0.x, b2f(qu.s[1]) + r0.y);
            rr.u.y = pack2(b2f(qu.s[2]) + r0.z, b2f(qu.s[3]) + r0.w);
            rr.u.z = pack2(b2f(qu.s[4]) + r1.x, b2f(qu.s[5]) + r1.y);
            rr.u.w = pack2(b2f(qu.s[6]) + r1.z, b2f(qu.s[7]) + r1.w);
            aw[ks] = ww.v;
            ar[ks] = rr.v;
        }
    }

    auto stage_chunk = [&](int cc) {
#pragma unroll
        for (int j = 0; j < 2; j++) {      // K tile [kv][d]
            int row = j * 32 + wave * 8 + lr8;
            gl_lds16(Kb + ((size_t)(n * SEQ + cc + row)) * EMB + h * HD + swz,
                     &Ks[(j * 32 + wave * 8) * 64]);
        }
#pragma unroll
        for (int j = 0; j < 2; j++) {      // V^T tile [d][kv]
            int row = j * 32 + wave * 8 + lr8;
            gl_lds16(Vtg + (((size_t)(n * NH + h) * HD + row) << 9) + cc + swz,
                     &Vt[(j * 32 + wave * 8) * 64]);
        }
#pragma unroll
        for (int j = 0; j < 4; j++) {      // R band rows t0..t0+127, t0 = q0-cc+448 in [0,1023]
            int row = j * 32 + wave * 8 + lr8;
            gl_lds16(Rb + (size_t)(q0 - cc + 448 + row) * EMB + h * HD + swz,
                     &Rs[(j * 32 + wave * 8) * 64]);
        }
    };

    float ls[4] = {0.f, 0.f, 0.f, 0.f};
    f32x4 acco[4] = {};

    stage_chunk(0);
    for (int c0 = 0; c0 < SEQ; c0 += 64) {
        __syncthreads();  // staging complete (vmcnt drained at barrier); prior LDS reads done

        f32x4 sacc[4] = {};
        f32x4 pacc[5] = {};
        bf16x8 vf[2][4];
#pragma unroll
        for (int ks = 0; ks < 2; ks++) {
            int pb = (ks * 4 + lq) ^ (lrow & 7);
#pragma unroll
            for (int ct = 0; ct < 4; ct++) {
                bf16x8 bk = *(const bf16x8*)&Ks[(ct * 16 + lrow) * 64 + pb * 8];
                sacc[ct] = __builtin_amdgcn_mfma_f32_16x16x32_bf16(aw[ks], bk, sacc[ct], 0, 0, 0);
            }
#pragma unroll
            for (int jj = 0; jj < 5; jj++) {
                bf16x8 br = *(const bf16x8*)&Rs[((wave + jj) * 16 + lrow) * 64 + pb * 8];
                pacc[jj] = __builtin_amdgcn_mfma_f32_16x16x32_bf16(ar[ks], br, pacc[jj], 0, 0, 0);
            }
#pragma unroll
            for (int dt = 0; dt < 4; dt++)
                vf[ks][dt] = *(const bf16x8*)&Vt[(dt * 16 + lrow) * 64 + pb * 8];
        }
        __syncthreads();  // all waves done reading Ks/Vt/Rs
        if (c0 + 64 < SEQ) stage_chunk(c0 + 64);  // overlaps the softmax/PV phase below

        // scatter banded P transposed: Psd[jwin][qlocal], one b64 per jj (wave-private region)
#pragma unroll
        for (int jj = 0; jj < 5; jj++) {
            ushort4 pk;
            pk.x = f2b(pacc[jj][0]); pk.y = f2b(pacc[jj][1]);
            pk.z = f2b(pacc[jj][2]); pk.w = f2b(pacc[jj][3]);
            *(ushort4*)&psd[(jj * 16 + lrow) * 20 + lq * 4] = pk;
        }

        // gather bd (all reads before Pb overwrites the region; in-order per-wave DS)
        float bd[4][4];
#pragma unroll
        for (int ct = 0; ct < 4; ct++)
#pragma unroll
            for (int r = 0; r < 4; r++) {
                int jwin = lq * 4 + r - (ct * 16 + lrow) + 63;  // in [0,78]
                bd[ct][r] = b2f(psd[jwin * 20 + lq * 4 + r]);
            }
        // p = 2^((ac+bd)*0.125/ln2) (no max subtraction), row-sum, store Pb[qlocal][k]
#pragma unroll
        for (int ct = 0; ct < 4; ct++)
#pragma unroll
            for (int r = 0; r < 4; r++) {
                float p = exp2f((sacc[ct][r] + bd[ct][r]) * 0.18033688011f);
                ls[r] += p;
                psd[(lq * 4 + r) * 72 + ct * 16 + lrow] = f2b(p);
            }

        // PV operand-swapped: A = V-frag (d rows), B = P-frag (q rows) -> acco[dt] = O[d][q]
#pragma unroll
        for (int ks = 0; ks < 2; ks++) {
            bf16x8 pf = *(const bf16x8*)&psd[lrow * 72 + ks * 32 + lq * 8];
#pragma unroll
            for (int dt = 0; dt < 4; dt++)
                acco[dt] = __builtin_amdgcn_mfma_f32_16x16x32_bf16(vf[ks][dt], pf, acco[dt], 0, 0, 0);
        }
    }

    // epilogue: reduce ls over the 16 k-lanes, broadcast by q via dead Rs, ushort4 stores
#pragma unroll
    for (int r = 0; r < 4; r++) {
#pragma unroll
        for (int msk = 1; msk < 16; msk <<= 1)
            ls[r] += __shfl_xor(ls[r], msk);
    }
    float* lsb = (float*)Rs;
    if (lrow == 0) {
#pragma unroll
        for (int r = 0; r < 4; r++)
            lsb[wave * 16 + lq * 4 + r] = ls[r];
    }
    float inv = 1.0f / lsb[wave * 16 + lrow];  // wave-private write->read, in-order DS
    int q = q0 + wave * 16 + lrow;
#pragma unroll
    for (int dt = 0; dt < 4; dt++) {
        ushort4 pk;
        pk.x = f2b(acco[dt][0] * inv);
        pk.y = f2b(acco[dt][1] * inv);
        pk.z = f2b(acco[dt][2] * inv);
        pk.w = f2b(acco[dt][3] * inv);
        *(ushort4*)&Ctx[((size_t)(n * SEQ + q)) * EMB + h * HD + dt * 16 + lq * 4] = pk;
    }
}

// ----------------------------------------------------------------
extern "C" void kernel_launch(void* const* d_in, const int* in_sizes, int n_in,
                              void* d_out, int out_size, void* d_ws, size_t ws_size,
                              hipStream_t stream) {
    const float* values = (const float*)d_in[0];
    const float* keys   = (const float*)d_in[1];
    const float* query  = (const float*)d_in[2];
    const float* Wq = (const float*)d_in[3];
    const float* bq = (const float*)d_in[4];
    const float* Wk = (const float*)d_in[5];
    const float* bk = (const float*)d_in[6];
    const float* Wv = (const float*)d_in[7];
    const float* bv = (const float*)d_in[8];
    const float* Wo = (const float*)d_in[9];
    const float* bo = (const float*)d_in[10];
    const float* Wpos = (const float*)d_in[11];
    const float* bpos = (const float*)d_in[12];
    const float* rwb = (const float*)d_in[13];
    const float* rrb = (const float*)d_in[14];
    float* out = (float*)d_out;

    u16* ws = (u16*)d_ws;
    size_t off = 0;
    u16* Wt = ws;            off += (size_t)5 * EMB * EMB;   // Wq^T,Wk^T,Wv^T,Wo^T,Wpos^T (bf16)
    u16* pe = ws + off;      off += (size_t)PEROWS * EMB;
    u16* Rb = ws + off;      off += (size_t)PEROWS * EMB;
    u16* qc = ws + off;      off += (size_t)NLROWS * EMB;    // bf16 query
    u16* kc = ws + off;      off += (size_t)NLROWS * EMB;    // bf16 keys
    u16* vc = ws + off;      off += (size_t)NLROWS * EMB;    // bf16 values
    u16* Qp = ws + off;      off += (size_t)NLROWS * EMB;    // Q projection
    u16* Kp = ws + off;      off += (size_t)NLROWS * EMB;    // K projection
    u16* Vtg = ws + off;     off += (size_t)NLROWS * EMB;    // V^T per (n,h): [n][h][d][kv]
    u16* Cx = qc;            // attention output (qc dead after fused GEMM dispatch)

    prep<<<dim3(8512), dim3(256), 0, stream>>>(Wq, Wk, Wv, Wo, Wpos, Wt, pe,
                                               query, keys, values, qc, kc, vc);

    // fused Q/K/V/R projection GEMMs: z = 0:Q 1:K 2:V(->V^T) 3:R(pe@Wpos, 1024 rows)
    gemm_k<128, 96, 4, false><<<dim3(32, 8, 4), dim3(256), 0, stream>>>(
        qc, kc, vc, pe,
        Wt, Wt + (size_t)1 * EMB * EMB, Wt + (size_t)2 * EMB * EMB, Wt + (size_t)4 * EMB * EMB,
        bq, bk, bv, bpos,
        Qp, Kp, Vtg, Rb);

    attn_rpe<<<dim3(8, NH, NB), dim3(256), 0, stream>>>(Qp, Kp, Vtg, Rb, rwb, rrb, Cx);

    gemm_k<64, 96, 1, true><<<dim3(64, 8), dim3(256), 0, stream>>>(
        Cx, Cx, Cx, Cx,
        Wt + (size_t)3 * EMB * EMB, Wt + (size_t)3 * EMB * EMB,
        Wt + (size_t)3 * EMB * EMB, Wt + (size_t)3 * EMB * EMB,
        bo, bo, bo, bo,
        out, out, out, out);
}